// Round 3
// baseline (349.316 us; speedup 1.0000x reference)
//
#include <hip/hip_runtime.h>

// BaggingMaxPool: out[d] = mean_k( max_{r in indices[k,:]} inp[r][d] )
// N=1024 rows, D=100000 cols, K=20 rounds, SELECT_N=256.
//
// Single streaming pass over inp (410 MB). Per-row 20-bit round-membership
// mask in LDS (wave-uniform per row -> readfirstlane -> uniform scalar
// branches; avg popcount ~4.4 of 20 rounds taken per row).
//
// __launch_bounds__(64, 1): round-2 kernel allocated only 52 VGPRs (default
// ~8-waves/EU heuristic) and spilled acc[20]+tiles (>=72 live) to scratch ->
// 167us of VALU spill traffic. With (64,1) the register file is open (grid
// is only 0.76 waves/SIMD anyway), so acc[20] float2 (40 VGPR) + 2x16x2
// tile buffers (64 VGPR) stay in registers.
// TILE=16 double-buffered: 16-32 outstanding 8B loads/thread (~2400 cyc of
// HBM latency cover) since waves/SIMD < 1 leaves only ILP for hiding.

#define N_ROWS   1024
#define D_COLS   100000
#define K_ROUNDS 20
#define SEL_N    256
#define NIDX     (K_ROUNDS * SEL_N)   // 5120
#define VEC      2
#define NTHREADS (D_COLS / VEC)       // 50000
#define BLOCK    64
#define TILE     16

__device__ __forceinline__ void load_tile(float2 (&v)[TILE], const float* __restrict__ p, int r0) {
    #pragma unroll
    for (int j = 0; j < TILE; ++j) {
        v[j] = *reinterpret_cast<const float2*>(p + (size_t)(r0 + j) * D_COLS);
    }
}

__device__ __forceinline__ void process_tile(const float2 (&v)[TILE], int r0,
                                             const unsigned int* smask,
                                             float2 (&acc)[K_ROUNDS]) {
    #pragma unroll
    for (int j = 0; j < TILE; ++j) {
        unsigned int m = (unsigned int)__builtin_amdgcn_readfirstlane((int)smask[r0 + j]);
        #pragma unroll
        for (int k = 0; k < K_ROUNDS; ++k) {
            if (m & (1u << k)) {
                acc[k].x = fmaxf(acc[k].x, v[j].x);
                acc[k].y = fmaxf(acc[k].y, v[j].y);
            }
        }
    }
}

__global__ __launch_bounds__(BLOCK, 1) void bagmax_kernel(
    const float* __restrict__ inp,
    const int*   __restrict__ indices,
    float*       __restrict__ out)
{
    __shared__ unsigned int smask[N_ROWS];
    const int tid = threadIdx.x;  // 0..63

    // --- build per-row round-membership mask in LDS (idx reads are L2/L3-hot) ---
    #pragma unroll
    for (int i = tid; i < N_ROWS; i += BLOCK) smask[i] = 0u;
    __syncthreads();
    for (int i = tid; i < NIDX; i += BLOCK) {
        int r = indices[i];
        int k = i >> 8;              // i / SEL_N
        atomicOr(&smask[r], 1u << k);
    }
    __syncthreads();

    const int t = blockIdx.x * BLOCK + tid;
    if (t >= NTHREADS) return;       // no __syncthreads after this point
    const int col = t * VEC;
    const float* p = inp + col;

    float2 acc[K_ROUNDS];
    #pragma unroll
    for (int k = 0; k < K_ROUNDS; ++k)
        acc[k] = make_float2(-3.402823466e+38f, -3.402823466e+38f);

    // --- streaming pass over all 1024 rows, software-pipelined in 16-row tiles ---
    float2 va[TILE], vb[TILE];
    load_tile(va, p, 0);
    #pragma unroll 1
    for (int r0 = 0; r0 < N_ROWS; r0 += 2 * TILE) {
        load_tile(vb, p, r0 + TILE);
        process_tile(va, r0, smask, acc);
        if (r0 + 2 * TILE < N_ROWS) load_tile(va, p, r0 + 2 * TILE);
        process_tile(vb, r0 + TILE, smask, acc);
    }

    // --- mean over rounds ---
    float2 s = make_float2(0.f, 0.f);
    #pragma unroll
    for (int k = 0; k < K_ROUNDS; ++k) {
        s.x += acc[k].x; s.y += acc[k].y;
    }
    const float inv = 1.0f / (float)K_ROUNDS;
    s.x *= inv; s.y *= inv;
    *reinterpret_cast<float2*>(out + col) = s;
}

extern "C" void kernel_launch(void* const* d_in, const int* in_sizes, int n_in,
                              void* d_out, int out_size, void* d_ws, size_t ws_size,
                              hipStream_t stream) {
    const float* inp     = (const float*)d_in[0];
    const int*   indices = (const int*)d_in[1];
    float*       out     = (float*)d_out;

    const int grid = (NTHREADS + BLOCK - 1) / BLOCK;  // 782
    bagmax_kernel<<<grid, BLOCK, 0, stream>>>(inp, indices, out);
}

// Round 4
// 179.688 us; speedup vs baseline: 1.9440x; 1.9440x over previous
//
#include <hip/hip_runtime.h>

// BaggingMaxPool: out[d] = mean_k( max_{r in indices[k,:]} inp[r][d] )
// N=1024 rows, D=100000 cols, K=20 rounds, SELECT_N=256.
//
// Round-4 restructure: rounds 1-3 died on compiler codegen for the branchy
// sparse-update (statement-level `if (m&bit)` x320 per tile -> spills +
// broken prefetch, 28x VALU overhead). This version is dense BRANCHLESS:
//   acc[k] = fmaxf(acc[k], (m & 1u<<k) ? v : -INF)
// (expression select on a readfirstlane'd uniform -> s_cselect+v_cndmask,
// no control flow). Dense VALU = 2.048e9 updates x 2 ops = ~52us chip-wide,
// under the ~65us memory floor.
//
// Parallelism: VEC=1, BLOCK=256 = 4 waves; each wave owns 256 of the 1024
// rows for the block's 64 columns; LDS partial-max reduce at the end.
// -> 1563 blocks x 4 waves = 6.1 waves/SIMD (TLP latency hiding), acc[20]
// floats = 20 VGPR, total ~45 VGPR: no spill risk at any occupancy.

#define N_ROWS   1024
#define D_COLS   100000
#define K_ROUNDS 20
#define SEL_N    256
#define NIDX     (K_ROUNDS * SEL_N)   // 5120
#define BLOCK    256
#define WAVES    4
#define RPW      (N_ROWS / WAVES)     // 256 rows per wave
#define NEG_INF  (-3.402823466e+38f)

__global__ __launch_bounds__(BLOCK, 4) void bagmax_kernel(
    const float* __restrict__ inp,
    const int*   __restrict__ indices,
    float*       __restrict__ out)
{
    __shared__ unsigned int smask[N_ROWS];
    __shared__ float part[WAVES - 1][K_ROUNDS][64];

    const int tid  = threadIdx.x;
    const int lane = tid & 63;
    const int wave = tid >> 6;

    // --- per-row 20-bit round-membership mask (indices are L2/L3-hot) ---
    for (int i = tid; i < N_ROWS; i += BLOCK) smask[i] = 0u;
    __syncthreads();
    for (int i = tid; i < NIDX; i += BLOCK) {
        atomicOr(&smask[indices[i]], 1u << (i >> 8));   // i>>8 == i/SEL_N
    }
    __syncthreads();

    const int col  = blockIdx.x * 64 + lane;
    const int colc = col < D_COLS ? col : D_COLS - 1;   // clamp; store guarded
    const float* p = inp + colc;
    const int r0   = wave * RPW;

    float acc[K_ROUNDS];
    #pragma unroll
    for (int k = 0; k < K_ROUNDS; ++k) acc[k] = NEG_INF;

    // --- stream this wave's 256 rows, 2-deep rolling prefetch (data+mask) ---
    float v0 = p[(size_t)(r0 + 0) * D_COLS];
    float v1 = p[(size_t)(r0 + 1) * D_COLS];
    unsigned int m0 = smask[r0 + 0];
    unsigned int m1 = smask[r0 + 1];

    #pragma unroll 4
    for (int r = 0; r < RPW; ++r) {
        const int rn = (r + 2 < RPW) ? (r + 2) : (RPW - 1);   // branchless tail
        float        v2 = p[(size_t)(r0 + rn) * D_COLS];
        unsigned int m2 = smask[r0 + rn];

        const unsigned int m =
            (unsigned int)__builtin_amdgcn_readfirstlane((int)m0);
        #pragma unroll
        for (int k = 0; k < K_ROUNDS; ++k) {
            const float sel = (m & (1u << k)) ? v0 : NEG_INF;  // uniform select
            acc[k] = fmaxf(acc[k], sel);
        }
        v0 = v1; v1 = v2;
        m0 = m1; m1 = m2;
    }

    // --- cross-wave max reduce in LDS, then mean over rounds ---
    if (wave > 0) {
        #pragma unroll
        for (int k = 0; k < K_ROUNDS; ++k) part[wave - 1][k][lane] = acc[k];
    }
    __syncthreads();
    if (wave == 0) {
        float s = 0.f;
        #pragma unroll
        for (int k = 0; k < K_ROUNDS; ++k) {
            const float a = fmaxf(acc[k],          part[0][k][lane]);
            const float b = fmaxf(part[1][k][lane], part[2][k][lane]);
            s += fmaxf(a, b);
        }
        if (col < D_COLS) out[col] = s * (1.0f / (float)K_ROUNDS);
    }
}

extern "C" void kernel_launch(void* const* d_in, const int* in_sizes, int n_in,
                              void* d_out, int out_size, void* d_ws, size_t ws_size,
                              hipStream_t stream) {
    const float* inp     = (const float*)d_in[0];
    const int*   indices = (const int*)d_in[1];
    float*       out     = (float*)d_out;

    const int grid = (D_COLS + 63) / 64;   // 1563 blocks of 64 cols
    bagmax_kernel<<<grid, BLOCK, 0, stream>>>(inp, indices, out);
}

// Round 5
// 137.844 us; speedup vs baseline: 2.5341x; 1.3036x over previous
//
#include <hip/hip_runtime.h>

// BaggingMaxPool: out[d] = mean_k( max_{r in indices[k,:]} inp[r][d] )
// N=1024 rows, D=100000 cols, K=20 rounds, SELECT_N=256.
//
// Structure (proven in round 4): single streaming pass, per-row 20-bit
// round-membership mask in LDS, dense BRANCHLESS selects on a
// readfirstlane'd uniform mask, 4 waves/block row-split (256 rows each),
// LDS cross-wave max reduce.
//
// Round-5 deltas:
//  - v_max3 pairing: chunks of 4 rows, acc = max3(acc, sel0, sel1) twice
//    -> 1.5 VALU/element vs 2.0 (dense VALU ~55us -> ~42us chip-wide).
//  - 4-row double-buffered register prefetch with STATIC indices (named
//    A/B buffers, no rolling copies) -> 4-8 outstanding loads/thread.
//  - VEC=2 (dwordx2): half the VMEM instrs + half the per-element mask/
//    loop overhead. acc[20] float2 = 40 VGPR, tiles 16 -> ~95 live VGPR,
//    fits __launch_bounds__(256,4)'s 128-VGPR budget without spill.

#define N_ROWS   1024
#define D_COLS   100000
#define K_ROUNDS 20
#define SEL_N    256
#define NIDX     (K_ROUNDS * SEL_N)   // 5120
#define VEC      2
#define CPB      (64 * VEC)           // 128 cols per block
#define BLOCK    256
#define WAVES    4
#define RPW      (N_ROWS / WAVES)     // 256 rows per wave
#define CHUNK    4
#define NEG_INF  (-3.402823466e+38f)

__device__ __forceinline__ void load_chunk(float2 (&v)[CHUNK], unsigned int (&m)[CHUNK],
                                           const float* __restrict__ p,
                                           const unsigned int* smask,
                                           int r0, int base) {
    #pragma unroll
    for (int j = 0; j < CHUNK; ++j) {
        v[j] = *reinterpret_cast<const float2*>(p + (size_t)(r0 + base + j) * D_COLS);
        m[j] = smask[r0 + base + j];
    }
}

__device__ __forceinline__ void process_chunk(const float2 (&v)[CHUNK],
                                              const unsigned int (&mm)[CHUNK],
                                              float2 (&acc)[K_ROUNDS]) {
    const unsigned int s0 = (unsigned int)__builtin_amdgcn_readfirstlane((int)mm[0]);
    const unsigned int s1 = (unsigned int)__builtin_amdgcn_readfirstlane((int)mm[1]);
    const unsigned int s2 = (unsigned int)__builtin_amdgcn_readfirstlane((int)mm[2]);
    const unsigned int s3 = (unsigned int)__builtin_amdgcn_readfirstlane((int)mm[3]);
    #pragma unroll
    for (int k = 0; k < K_ROUNDS; ++k) {
        const unsigned int bit = 1u << k;
        const float a0x = (s0 & bit) ? v[0].x : NEG_INF;
        const float a0y = (s0 & bit) ? v[0].y : NEG_INF;
        const float a1x = (s1 & bit) ? v[1].x : NEG_INF;
        const float a1y = (s1 & bit) ? v[1].y : NEG_INF;
        const float a2x = (s2 & bit) ? v[2].x : NEG_INF;
        const float a2y = (s2 & bit) ? v[2].y : NEG_INF;
        const float a3x = (s3 & bit) ? v[3].x : NEG_INF;
        const float a3y = (s3 & bit) ? v[3].y : NEG_INF;
        acc[k].x = fmaxf(fmaxf(acc[k].x, a0x), a1x);   // -> v_max3
        acc[k].y = fmaxf(fmaxf(acc[k].y, a0y), a1y);
        acc[k].x = fmaxf(fmaxf(acc[k].x, a2x), a3x);
        acc[k].y = fmaxf(fmaxf(acc[k].y, a2y), a3y);
    }
}

__global__ __launch_bounds__(BLOCK, 4) void bagmax_kernel(
    const float* __restrict__ inp,
    const int*   __restrict__ indices,
    float*       __restrict__ out)
{
    __shared__ unsigned int smask[N_ROWS];
    __shared__ float2 part[WAVES - 1][K_ROUNDS][64];   // 30 KB

    const int tid  = threadIdx.x;
    const int lane = tid & 63;
    const int wave = tid >> 6;

    // --- per-row 20-bit round-membership mask (indices are L2/L3-hot) ---
    for (int i = tid; i < N_ROWS; i += BLOCK) smask[i] = 0u;
    __syncthreads();
    for (int i = tid; i < NIDX; i += BLOCK) {
        atomicOr(&smask[indices[i]], 1u << (i >> 8));   // i>>8 == i/SEL_N
    }
    __syncthreads();

    const int colbase = blockIdx.x * CPB + lane * VEC;
    const int colc    = colbase <= D_COLS - VEC ? colbase : D_COLS - VEC;  // clamp loads
    const float* p    = inp + colc;
    const int r0      = wave * RPW;

    float2 acc[K_ROUNDS];
    #pragma unroll
    for (int k = 0; k < K_ROUNDS; ++k) acc[k] = make_float2(NEG_INF, NEG_INF);

    // --- stream this wave's 256 rows: 4-row chunks, double-buffered ---
    float2 A[CHUNK], B[CHUNK];
    unsigned int mA[CHUNK], mB[CHUNK];
    load_chunk(A, mA, p, smask, r0, 0);
    #pragma unroll 1
    for (int c = 0; c < RPW; c += 2 * CHUNK) {
        load_chunk(B, mB, p, smask, r0, c + CHUNK);
        process_chunk(A, mA, acc);
        const int nb = (c + 2 * CHUNK <= RPW - CHUNK) ? (c + 2 * CHUNK) : (RPW - CHUNK);
        load_chunk(A, mA, p, smask, r0, nb);   // last iter: redundant reload, never processed twice
        process_chunk(B, mB, acc);
    }

    // --- cross-wave max reduce in LDS, then mean over rounds ---
    if (wave > 0) {
        #pragma unroll
        for (int k = 0; k < K_ROUNDS; ++k) part[wave - 1][k][lane] = acc[k];
    }
    __syncthreads();
    if (wave == 0) {
        float sx = 0.f, sy = 0.f;
        #pragma unroll
        for (int k = 0; k < K_ROUNDS; ++k) {
            const float2 p0 = part[0][k][lane];
            const float2 p1 = part[1][k][lane];
            const float2 p2 = part[2][k][lane];
            sx += fmaxf(fmaxf(acc[k].x, p0.x), fmaxf(p1.x, p2.x));
            sy += fmaxf(fmaxf(acc[k].y, p0.y), fmaxf(p1.y, p2.y));
        }
        if (colbase <= D_COLS - VEC) {
            *reinterpret_cast<float2*>(out + colbase) =
                make_float2(sx * (1.0f / K_ROUNDS), sy * (1.0f / K_ROUNDS));
        }
    }
}

extern "C" void kernel_launch(void* const* d_in, const int* in_sizes, int n_in,
                              void* d_out, int out_size, void* d_ws, size_t ws_size,
                              hipStream_t stream) {
    const float* inp     = (const float*)d_in[0];
    const int*   indices = (const int*)d_in[1];
    float*       out     = (float*)d_out;

    const int grid = (D_COLS + CPB - 1) / CPB;   // 782
    bagmax_kernel<<<grid, BLOCK, 0, stream>>>(inp, indices, out);
}